// Round 1
// baseline (1277.484 us; speedup 1.0000x reference)
//
#include <hip/hip_runtime.h>

// Problem constants (match reference)
#define K_     1056
#define N_     2112
#define M_     1056   // N - K
#define E_     6336   // M * (DV+1)
#define DV_    5
#define ROW_   6      // DV + 1 edges per check, contiguous
#define NSYM_  528
#define NITER_ 20
#define BATCH_ 1024
#define DMAX_  32     // max VN degree we support (Poisson(5) tail << 32)

// -------------------------------------------------------------------------
// Build deterministic VN->edge CSR (fixed-stride layout adj[d][v], v-major
// for coalescing). Edge ids are stored TRANSFORMED to the [j][M] c2v layout:
// loc(e) = (e%6)*M + e/6.  Lists are ascending in original edge id, which
// reproduces np.add.at accumulation order per variable node exactly.
// Parity VNs (v >= K) have degree 1 with edge 6m+5 — direct formula.
// -------------------------------------------------------------------------
__global__ void build_csr_kernel(const int* __restrict__ edge_vn,
                                 unsigned short* __restrict__ adj,
                                 int* __restrict__ deg) {
    int v = blockIdx.x * blockDim.x + threadIdx.x;
    if (v >= N_) return;
    if (v >= K_) {
        int m = v - K_;
        adj[v] = (unsigned short)(5 * M_ + m);   // d = 0 slot
        deg[v] = 1;
        return;
    }
    int d = 0;
    for (int e = 0; e < E_; ++e) {
        if (edge_vn[e] == v) {
            if (d < DMAX_) {
                int m = e / ROW_;
                int j = e - m * ROW_;
                adj[d * N_ + v] = (unsigned short)(j * M_ + m);
            }
            ++d;
        }
    }
    deg[v] = (d < DMAX_) ? d : DMAX_;
}

// -------------------------------------------------------------------------
// One block per codeword. All state in LDS:
//   s_llr[N]  : first holds codeword bits (as float 0/1), then demapped LLRs
//   s_c2v[E]  : check->variable messages, laid out [j][M] (conflict-free CN)
// -------------------------------------------------------------------------
__global__ __launch_bounds__(256, 4) void link_kernel(
    const int*   __restrict__ bits,      // [B,K] int32
    const int*   __restrict__ a_idx,     // [M,DV] int32
    const float* __restrict__ points_re, // [16]
    const float* __restrict__ points_im, // [16]
    const float* __restrict__ noise_re,  // [B,NSYM]
    const float* __restrict__ noise_im,  // [B,NSYM]
    const float* __restrict__ ebno_db,   // [1]
    const unsigned short* __restrict__ adj, // [DMAX][N]
    const int*   __restrict__ deg,       // [N]
    float*       __restrict__ out)       // [2,B,K]
{
#pragma clang fp contract(off)
    const int b   = blockIdx.x;
    const int tid = threadIdx.x;
    const int bs  = blockDim.x;

    __shared__ float s_llr[N_];
    __shared__ float s_c2v[E_];
    __shared__ float s_pre[16];
    __shared__ float s_pim[16];

    if (tid < 16) {
        s_pre[tid] = points_re[tid];
        s_pim[tid] = points_im[tid];
    }

    // noise variance per reference: no = 1/(10^(EbN0/10) * coderate * NBPS)
    const float eb    = ebno_db[0];
    const float no    = 1.0f / ((powf(10.0f, eb / 10.0f) * 0.5f) * 4.0f);
    const float sigma = sqrtf(no / 2.0f);

    // ---- load info bits (as float 0/1), emit output0 = bits.astype(f32) ----
    for (int i = tid; i < K_; i += bs) {
        int v = bits[b * K_ + i];
        s_llr[i] = (float)v;
        out[b * K_ + i] = (float)v;
    }
    __syncthreads();

    // ---- parity bits: XOR of DV gathered info bits ----
    for (int m = tid; m < M_; m += bs) {
        float acc = 0.0f;
        #pragma unroll
        for (int d = 0; d < DV_; ++d) acc += s_llr[a_idx[m * DV_ + d]];
        s_llr[K_ + m] = (float)(((int)acc) & 1);
    }
    __syncthreads();

    // ---- QAM map + AWGN + exact APP demap (per symbol; 4 LLRs out) ----
    for (int s = tid; s < NSYM_; s += bs) {
        int c0 = (int)s_llr[4 * s + 0];
        int c1 = (int)s_llr[4 * s + 1];
        int c2 = (int)s_llr[4 * s + 2];
        int c3 = (int)s_llr[4 * s + 3];
        int sym = c0 * 8 + c1 * 4 + c2 * 2 + c3;
        float yre = s_pre[sym] + sigma * noise_re[b * NSYM_ + s];
        float yim = s_pim[sym] + sigma * noise_im[b * NSYM_ + s];
        float lg[16];
        #pragma unroll
        for (int p = 0; p < 16; ++p) {
            float dre  = yre - s_pre[p];
            float dim_ = yim - s_pim[p];
            float d2   = dre * dre + dim_ * dim_;   // no FMA (contract off)
            lg[p] = -d2 / no;
        }
        float llr4[4];
        #pragma unroll
        for (int j = 0; j < 4; ++j) {
            float m0 = -1e30f, m1 = -1e30f;
            #pragma unroll
            for (int p = 0; p < 16; ++p) {
                if (((p >> (3 - j)) & 1) == 0) m0 = fmaxf(m0, lg[p]);
                else                           m1 = fmaxf(m1, lg[p]);
            }
            float sum0 = 0.0f, sum1 = 0.0f;
            #pragma unroll
            for (int p = 0; p < 16; ++p) {     // ascending order == np order
                if (((p >> (3 - j)) & 1) == 0) sum0 += expf(lg[p] - m0);
                else                           sum1 += expf(lg[p] - m1);
            }
            llr4[j] = (m0 + logf(sum0)) - (m1 + logf(sum1));
        }
        // overwrite the 4 cw slots this thread owns with the LLRs
        s_llr[4 * s + 0] = llr4[0];
        s_llr[4 * s + 1] = llr4[1];
        s_llr[4 * s + 2] = llr4[2];
        s_llr[4 * s + 3] = llr4[3];
    }
    // init c2v = 0 (independent of demap)
    for (int e = tid; e < E_; e += bs) s_c2v[e] = 0.0f;
    __syncthreads();

    // ---- sum-product BP, flooding, NITER iterations ----
    for (int it = 0; it < NITER_; ++it) {
        // Phase A: VN-centric. mg = sum(c2v) (np.add.at order), then
        // in-place c2v[e] <- (llr + mg) - c2v[e]  (now holds v2c).
        for (int v = tid; v < N_; v += bs) {
            int dg = deg[v];
            float mg = 0.0f;
            for (int d = 0; d < dg; ++d) mg += s_c2v[adj[d * N_ + v]];
            float t = s_llr[v] + mg;
            for (int d = 0; d < dg; ++d) {
                int loc = adj[d * N_ + v];
                s_c2v[loc] = t - s_c2v[loc];
            }
        }
        __syncthreads();
        // Phase B: CN-centric, 6 local edges, no shared scratch.
        for (int m = tid; m < M_; m += bs) {
            float lt[ROW_];
            float cs = 0.0f;
            int sg = 0;
            #pragma unroll
            for (int j = 0; j < ROW_; ++j) {
                float v2c = s_c2v[j * M_ + m];
                float av  = fminf(fmaxf(fabsf(v2c), 1e-6f), 20.0f);
                lt[j] = logf(tanhf(av * 0.5f));
                sg |= (v2c < 0.0f) ? (1 << j) : 0;
                cs += lt[j];                       // ascending edge order
            }
            int ns = __popc(sg);
            #pragma unroll
            for (int j = 0; j < ROW_; ++j) {
                float arg = fminf(cs - lt[j], -1e-7f);
                float ex  = expf(arg);
                float r   = 2.0f * atanhf(ex);
                int sgj = (sg >> j) & 1;
                if ((ns - sgj) & 1) r = -r;
                s_c2v[j * M_ + m] = r;
            }
        }
        __syncthreads();
    }

    // ---- final marginal + hard decision on info bits ----
    for (int v = tid; v < K_; v += bs) {
        int dg = deg[v];
        float mg = 0.0f;
        for (int d = 0; d < dg; ++d) mg += s_c2v[adj[d * N_ + v]];
        float tot = s_llr[v] + mg;
        out[(size_t)BATCH_ * K_ + b * K_ + v] = (tot < 0.0f) ? 1.0f : 0.0f;
    }
}

extern "C" void kernel_launch(void* const* d_in, const int* in_sizes, int n_in,
                              void* d_out, int out_size, void* d_ws, size_t ws_size,
                              hipStream_t stream) {
    const int*   bits    = (const int*)  d_in[0];
    const int*   a_idx   = (const int*)  d_in[1];
    // d_in[2] = edge_cn (implicit: contiguous groups of 6) — unused
    const int*   edge_vn = (const int*)  d_in[3];
    const float* pre     = (const float*)d_in[4];
    const float* pim     = (const float*)d_in[5];
    const float* nre     = (const float*)d_in[6];
    const float* nim     = (const float*)d_in[7];
    const float* ebno    = (const float*)d_in[8];

    unsigned short* adj = (unsigned short*)d_ws;                       // DMAX*N u16
    int*            deg = (int*)((char*)d_ws + (size_t)DMAX_ * N_ * sizeof(unsigned short));

    build_csr_kernel<<<(N_ + 255) / 256, 256, 0, stream>>>(edge_vn, adj, deg);
    link_kernel<<<BATCH_, 256, 0, stream>>>(bits, a_idx, pre, pim, nre, nim,
                                            ebno, adj, deg, (float*)d_out);
}

// Round 2
// 753.567 us; speedup vs baseline: 1.6952x; 1.6952x over previous
//
#include <hip/hip_runtime.h>

// Problem constants (match reference)
#define K_     1056
#define N_     2112
#define M_     1056   // N - K
#define E_     6336   // M * (DV+1)
#define DV_    5
#define ROW_   6      // DV + 1 edges per check, contiguous
#define NSYM_  528
#define NITER_ 20
#define BATCH_ 1024
#define DMAX_  24     // max VN degree supported (empirical max ~15 for this graph)

// -------------------------------------------------------------------------
// Parallel deterministic CSR build. One thread per edge.
// rank(e) = #{e' < e : edge_vn[e'] == edge_vn[e]}  -> slot in adj[rank][v].
// Ascending-edge order per VN reproduces np.add.at accumulation order.
// Also emits vnT[j*M+m] = vn of edge (m,j)  (the [j][M] c2v layout).
// Parity VNs (j==5) are degree-1 identity columns -> direct formula.
// -------------------------------------------------------------------------
__global__ __launch_bounds__(256) void build_adj_kernel(
    const int* __restrict__ edge_vn,
    unsigned short* __restrict__ adj,   // [DMAX][N]
    unsigned short* __restrict__ vnT,   // [ROW][M]
    int* __restrict__ deg)              // [N]
{
    __shared__ int s_evn[E_];
    for (int i = threadIdx.x; i < E_; i += blockDim.x) s_evn[i] = edge_vn[i];
    __syncthreads();
    int e = blockIdx.x * blockDim.x + threadIdx.x;
    if (e >= E_) return;
    int v = s_evn[e];
    int m = e / ROW_;
    int j = e - m * ROW_;
    vnT[j * M_ + m] = (unsigned short)v;
    if (j == ROW_ - 1) {                 // identity column
        adj[v] = (unsigned short)(5 * M_ + m);
        deg[v] = 1;
        return;
    }
    int before = 0, total = 0;
    for (int i = 0; i < E_; ++i) {       // broadcast LDS scan, lockstep
        int match = (s_evn[i] == v) ? 1 : 0;
        total += match;
        before += (i < e) ? match : 0;
    }
    if (before < DMAX_) adj[before * N_ + v] = (unsigned short)(j * M_ + m);
    deg[v] = (total < DMAX_) ? total : DMAX_;
}

// -------------------------------------------------------------------------
// One block per codeword. LDS state:
//   s_llr[N] : bits (0/1) during encode, then demapped channel LLRs
//   s_tot[N] : per-iteration VN marginals llr + sum(c2v)
//   s_c2v[E] : check->variable messages, [j][M] layout (CN phase coalesced)
// Fast-math identities (HW v_exp/v_log, ~1-2 ULP):
//   log(tanh(x/2)) = log((1-e^-x)/(1+e^-x))
//   2*atanh(y)     = log((1+y)/(1-y))
// -------------------------------------------------------------------------
__global__ __launch_bounds__(256) void link_kernel(
    const int*   __restrict__ bits,      // [B,K]
    const int*   __restrict__ a_idx,     // [M,DV]
    const float* __restrict__ points_re, // [16]
    const float* __restrict__ points_im, // [16]
    const float* __restrict__ noise_re,  // [B,NSYM]
    const float* __restrict__ noise_im,  // [B,NSYM]
    const float* __restrict__ ebno_db,   // [1]
    const unsigned short* __restrict__ adj,  // [DMAX][N]
    const unsigned short* __restrict__ vnT,  // [ROW][M]
    const int*   __restrict__ deg,       // [N]
    float*       __restrict__ out)       // [2,B,K]
{
#pragma clang fp contract(off)
    const int b   = blockIdx.x;
    const int tid = threadIdx.x;
    const int bs  = blockDim.x;

    __shared__ float s_llr[N_];
    __shared__ float s_tot[N_];
    __shared__ float s_c2v[E_];
    __shared__ float s_pre[16];
    __shared__ float s_pim[16];

    if (tid < 16) {
        s_pre[tid] = points_re[tid];
        s_pim[tid] = points_im[tid];
    }

    const float eb    = ebno_db[0];
    const float no    = 1.0f / ((powf(10.0f, eb / 10.0f) * 0.5f) * 4.0f);
    const float sigma = sqrtf(no / 2.0f);

    // ---- info bits; output0 = bits.astype(f32) ----
    for (int i = tid; i < K_; i += bs) {
        int v = bits[b * K_ + i];
        s_llr[i] = (float)v;
        out[b * K_ + i] = (float)v;
    }
    __syncthreads();

    // ---- parity: XOR of DV gathered info bits ----
    for (int m = tid; m < M_; m += bs) {
        float acc = 0.0f;
        #pragma unroll
        for (int d = 0; d < DV_; ++d) acc += s_llr[a_idx[m * DV_ + d]];
        s_llr[K_ + m] = (float)(((int)acc) & 1);
    }
    __syncthreads();

    // ---- QAM map + AWGN + exact APP demap ----
    for (int s = tid; s < NSYM_; s += bs) {
        int c0 = (int)s_llr[4 * s + 0];
        int c1 = (int)s_llr[4 * s + 1];
        int c2 = (int)s_llr[4 * s + 2];
        int c3 = (int)s_llr[4 * s + 3];
        int sym = c0 * 8 + c1 * 4 + c2 * 2 + c3;
        float yre = s_pre[sym] + sigma * noise_re[b * NSYM_ + s];
        float yim = s_pim[sym] + sigma * noise_im[b * NSYM_ + s];
        float lg[16];
        #pragma unroll
        for (int p = 0; p < 16; ++p) {
            float dre  = yre - s_pre[p];
            float dim_ = yim - s_pim[p];
            float d2   = dre * dre + dim_ * dim_;
            lg[p] = -d2 / no;
        }
        float llr4[4];
        #pragma unroll
        for (int j = 0; j < 4; ++j) {
            float m0 = -1e30f, m1 = -1e30f;
            #pragma unroll
            for (int p = 0; p < 16; ++p) {
                if (((p >> (3 - j)) & 1) == 0) m0 = fmaxf(m0, lg[p]);
                else                           m1 = fmaxf(m1, lg[p]);
            }
            float sum0 = 0.0f, sum1 = 0.0f;
            #pragma unroll
            for (int p = 0; p < 16; ++p) {
                if (((p >> (3 - j)) & 1) == 0) sum0 += __expf(lg[p] - m0);
                else                           sum1 += __expf(lg[p] - m1);
            }
            llr4[j] = (m0 + __logf(sum0)) - (m1 + __logf(sum1));
        }
        s_llr[4 * s + 0] = llr4[0];
        s_llr[4 * s + 1] = llr4[1];
        s_llr[4 * s + 2] = llr4[2];
        s_llr[4 * s + 3] = llr4[3];
    }
    for (int e = tid; e < E_; e += bs) s_c2v[e] = 0.0f;
    __syncthreads();

    // ---- sum-product BP, flooding ----
    for (int it = 0; it < NITER_; ++it) {
        // Phase A: VN marginals tot[v] = llr[v] + sum c2v (np.add.at order)
        for (int v = tid; v < N_; v += bs) {
            int dg = deg[v];
            float mg = 0.0f;
            for (int d = 0; d < dg; ++d) mg += s_c2v[adj[d * N_ + v]];
            s_tot[v] = s_llr[v] + mg;
        }
        __syncthreads();
        // Phase B: CN update, extrinsic subtraction fused (v2c in regs)
        for (int m = tid; m < M_; m += bs) {
            float lt[ROW_];
            float cs = 0.0f;
            int sg = 0;
            #pragma unroll
            for (int j = 0; j < ROW_; ++j) {
                int loc = j * M_ + m;
                float v2c = s_tot[vnT[loc]] - s_c2v[loc];
                float av  = fminf(fmaxf(fabsf(v2c), 1e-6f), 20.0f);
                float t   = __expf(-av);
                float l   = __logf(__fdividef(1.0f - t, 1.0f + t));
                lt[j] = l;
                sg |= (v2c < 0.0f) ? (1 << j) : 0;
                cs += l;
            }
            int ns = __popc(sg);
            #pragma unroll
            for (int j = 0; j < ROW_; ++j) {
                float arg = fminf(cs - lt[j], -1e-7f);
                float ex  = fminf(__expf(arg), 0.99999994f);   // keep < 1
                float r   = __logf(__fdividef(1.0f + ex, 1.0f - ex));
                int sgj = (sg >> j) & 1;
                if ((ns - sgj) & 1) r = -r;
                s_c2v[j * M_ + m] = r;
            }
        }
        __syncthreads();
    }

    // ---- final marginal + hard decision on info bits ----
    for (int v = tid; v < K_; v += bs) {
        int dg = deg[v];
        float mg = 0.0f;
        for (int d = 0; d < dg; ++d) mg += s_c2v[adj[d * N_ + v]];
        float tot = s_llr[v] + mg;
        out[(size_t)BATCH_ * K_ + b * K_ + v] = (tot < 0.0f) ? 1.0f : 0.0f;
    }
}

extern "C" void kernel_launch(void* const* d_in, const int* in_sizes, int n_in,
                              void* d_out, int out_size, void* d_ws, size_t ws_size,
                              hipStream_t stream) {
    const int*   bits    = (const int*)  d_in[0];
    const int*   a_idx   = (const int*)  d_in[1];
    // d_in[2] = edge_cn (implicit: contiguous groups of 6) — unused
    const int*   edge_vn = (const int*)  d_in[3];
    const float* pre     = (const float*)d_in[4];
    const float* pim     = (const float*)d_in[5];
    const float* nre     = (const float*)d_in[6];
    const float* nim     = (const float*)d_in[7];
    const float* ebno    = (const float*)d_in[8];

    char* ws = (char*)d_ws;
    unsigned short* adj = (unsigned short*)ws;                 // DMAX*N u16
    ws += (size_t)DMAX_ * N_ * sizeof(unsigned short);
    unsigned short* vnT = (unsigned short*)ws;                 // ROW*M u16
    ws += (size_t)ROW_ * M_ * sizeof(unsigned short);
    int* deg = (int*)ws;                                       // N i32

    build_adj_kernel<<<(E_ + 255) / 256, 256, 0, stream>>>(edge_vn, adj, vnT, deg);
    link_kernel<<<BATCH_, 256, 0, stream>>>(bits, a_idx, pre, pim, nre, nim,
                                            ebno, adj, vnT, deg, (float*)d_out);
}

// Round 3
// 468.667 us; speedup vs baseline: 2.7258x; 1.6079x over previous
//
#include <hip/hip_runtime.h>

// Problem constants (match reference)
#define K_     1056
#define N_     2112
#define M_     1056   // N - K
#define E_     6336   // M * (DV+1)
#define DV_    5
#define ROW_   6      // DV + 1 edges per check, contiguous
#define NSYM_  528
#define NITER_ 20
#define BATCH_ 1024
#define DMAX_  24     // max VN degree supported (Poisson(5); actual max ~15)

// -------------------------------------------------------------------------
// Wave-cooperative deterministic CSR build: one 64-lane wave per VN.
// Scan edge_vn in 64-entry windows; ballot gives the per-window match mask;
// rank(e) = running + popc(mask below lane)  ->  ascending-edge order, which
// reproduces np.add.at accumulation order exactly. Edge ids are stored
// transformed to the [j][M] c2v layout: loc(e) = (e%6)*M + e/6.
// Parity VNs (v >= K) are degree-1 identity columns -> direct formula.
// vnT[j*M+m] = vn of edge (m,j): 3 edges filled per block (N*3 == E).
// -------------------------------------------------------------------------
__global__ __launch_bounds__(64) void build_adj_kernel(
    const int* __restrict__ edge_vn,
    unsigned short* __restrict__ adj,   // [DMAX][N]
    unsigned short* __restrict__ vnT,   // [ROW][M]
    int* __restrict__ deg)              // [N]
{
    const int v    = blockIdx.x;
    const int lane = threadIdx.x;

    if (lane < 3) {                       // vnT fill: exactly 3 edges per block
        int e = 3 * v + lane;
        int m = e / ROW_, j = e - m * ROW_;
        vnT[j * M_ + m] = (unsigned short)edge_vn[e];
    }
    if (v >= K_) {
        if (lane == 0) {
            int m = v - K_;
            adj[v] = (unsigned short)(5 * M_ + m);
            deg[v] = 1;
        }
        return;
    }
    int running = 0;
    for (int w = 0; w < E_ / 64; ++w) {
        int e = w * 64 + lane;
        bool match = (edge_vn[e] == v);
        unsigned long long mask = __ballot(match);
        if (match) {
            int rank = running + __popcll(mask & ((1ull << lane) - 1ull));
            if (rank < DMAX_) {
                int m = e / ROW_, j = e - m * ROW_;
                adj[rank * N_ + v] = (unsigned short)(j * M_ + m);
            }
        }
        running += (int)__popcll(mask);
    }
    if (lane == 0) deg[v] = (running < DMAX_) ? running : DMAX_;
}

// -------------------------------------------------------------------------
// One block per codeword. LDS state (33.9 KB -> 4 blocks/CU):
//   s_tot[N] : bits (0/1) -> demapped LLRs -> per-iter VN marginals
//   s_c2v[E] : check->variable messages, [j][M] layout (CN phase coalesced)
// Channel LLRs live in registers (lr[9], VN ownership v = tid + 256k).
// Fast-math identities (HW v_exp/v_log, ~1-2 ULP):
//   log(tanh(x/2)) = log((1-e^-x)/(1+e^-x))
//   2*atanh(y)     = log((1+y)/(1-y))
// -------------------------------------------------------------------------
__global__ __launch_bounds__(256, 4) void link_kernel(
    const int*   __restrict__ bits,      // [B,K]
    const int*   __restrict__ a_idx,     // [M,DV]
    const float* __restrict__ points_re, // [16]
    const float* __restrict__ points_im, // [16]
    const float* __restrict__ noise_re,  // [B,NSYM]
    const float* __restrict__ noise_im,  // [B,NSYM]
    const float* __restrict__ ebno_db,   // [1]
    const unsigned short* __restrict__ adj,  // [DMAX][N]
    const unsigned short* __restrict__ vnT,  // [ROW][M]
    const int*   __restrict__ deg,       // [N]
    float*       __restrict__ out)       // [2,B,K]
{
#pragma clang fp contract(off)
    const int b   = blockIdx.x;
    const int tid = threadIdx.x;
    const int bs  = blockDim.x;

    __shared__ float s_tot[N_];
    __shared__ float s_c2v[E_];
    __shared__ float s_pre[16];
    __shared__ float s_pim[16];

    if (tid < 16) {
        s_pre[tid] = points_re[tid];
        s_pim[tid] = points_im[tid];
    }

    const float eb    = ebno_db[0];
    const float no    = 1.0f / ((powf(10.0f, eb / 10.0f) * 0.5f) * 4.0f);
    const float sigma = sqrtf(no / 2.0f);

    // ---- stage info bits (0/1 floats); output0 = bits.astype(f32) ----
    for (int i = tid; i < K_; i += bs) {
        int v = bits[b * K_ + i];
        s_tot[i] = (float)v;
        out[b * K_ + i] = (float)v;
    }
    __syncthreads();

    // ---- parity: XOR of DV gathered info bits ----
    for (int m = tid; m < M_; m += bs) {
        float acc = 0.0f;
        #pragma unroll
        for (int d = 0; d < DV_; ++d) acc += s_tot[a_idx[m * DV_ + d]];
        s_tot[K_ + m] = (float)(((int)acc) & 1);
    }
    __syncthreads();

    // ---- QAM map + AWGN + exact APP demap (in-place into s_tot) ----
    for (int s = tid; s < NSYM_; s += bs) {
        int c0 = (int)s_tot[4 * s + 0];
        int c1 = (int)s_tot[4 * s + 1];
        int c2 = (int)s_tot[4 * s + 2];
        int c3 = (int)s_tot[4 * s + 3];
        int sym = c0 * 8 + c1 * 4 + c2 * 2 + c3;
        float yre = s_pre[sym] + sigma * noise_re[b * NSYM_ + s];
        float yim = s_pim[sym] + sigma * noise_im[b * NSYM_ + s];
        float lg[16];
        #pragma unroll
        for (int p = 0; p < 16; ++p) {
            float dre  = yre - s_pre[p];
            float dim_ = yim - s_pim[p];
            float d2   = dre * dre + dim_ * dim_;
            lg[p] = -d2 / no;
        }
        float llr4[4];
        #pragma unroll
        for (int j = 0; j < 4; ++j) {
            float m0 = -1e30f, m1 = -1e30f;
            #pragma unroll
            for (int p = 0; p < 16; ++p) {
                if (((p >> (3 - j)) & 1) == 0) m0 = fmaxf(m0, lg[p]);
                else                           m1 = fmaxf(m1, lg[p]);
            }
            float sum0 = 0.0f, sum1 = 0.0f;
            #pragma unroll
            for (int p = 0; p < 16; ++p) {
                if (((p >> (3 - j)) & 1) == 0) sum0 += __expf(lg[p] - m0);
                else                           sum1 += __expf(lg[p] - m1);
            }
            llr4[j] = (m0 + __logf(sum0)) - (m1 + __logf(sum1));
        }
        s_tot[4 * s + 0] = llr4[0];
        s_tot[4 * s + 1] = llr4[1];
        s_tot[4 * s + 2] = llr4[2];
        s_tot[4 * s + 3] = llr4[3];
    }
    for (int e = tid; e < E_; e += bs) s_c2v[e] = 0.0f;
    __syncthreads();

    // ---- channel LLRs of owned VNs -> registers ----
    float lr[9];
    #pragma unroll
    for (int k = 0; k < 9; ++k) {
        int v = tid + 256 * k;
        lr[k] = (v < N_) ? s_tot[v] : 0.0f;
    }
    // no barrier needed: each s_tot slot is read/written only by its owner
    // until the next __syncthreads (Phase B readers are behind a barrier)

    // ---- sum-product BP, flooding ----
    for (int it = 0; it < NITER_; ++it) {
        // Phase A: tot[v] = llr[v] + sum c2v (ascending-edge = np.add.at order)
        #pragma unroll
        for (int k = 0; k < 9; ++k) {
            int v = tid + 256 * k;
            if (v < N_) {
                int dg = deg[v];
                float mg = 0.0f;
                for (int d = 0; d < dg; ++d) mg += s_c2v[adj[d * N_ + v]];
                s_tot[v] = lr[k] + mg;
            }
        }
        __syncthreads();
        // Phase B: CN update, extrinsic subtraction fused (v2c in regs)
        #pragma unroll
        for (int kk = 0; kk < 5; ++kk) {
            int m = tid + 256 * kk;
            if (m < M_) {
                float lt[ROW_];
                float cs = 0.0f;
                int sg = 0;
                #pragma unroll
                for (int j = 0; j < ROW_; ++j) {
                    int loc = j * M_ + m;
                    float v2c = s_tot[vnT[loc]] - s_c2v[loc];
                    float av  = fminf(fmaxf(fabsf(v2c), 1e-6f), 20.0f);
                    float t   = __expf(-av);
                    float l   = __logf(__fdividef(1.0f - t, 1.0f + t));
                    lt[j] = l;
                    sg |= (v2c < 0.0f) ? (1 << j) : 0;
                    cs += l;
                }
                int ns = __popc(sg);
                #pragma unroll
                for (int j = 0; j < ROW_; ++j) {
                    float arg = fminf(cs - lt[j], -1e-7f);
                    float ex  = fminf(__expf(arg), 0.99999994f);   // keep < 1
                    float r   = __logf(__fdividef(1.0f + ex, 1.0f - ex));
                    int sgj = (sg >> j) & 1;
                    if ((ns - sgj) & 1) r = -r;
                    s_c2v[j * M_ + m] = r;
                }
            }
        }
        __syncthreads();
    }

    // ---- final marginal + hard decision on owned info VNs (coalesced) ----
    #pragma unroll
    for (int k = 0; k < 5; ++k) {
        int v = tid + 256 * k;
        if (v < K_) {
            int dg = deg[v];
            float mg = 0.0f;
            for (int d = 0; d < dg; ++d) mg += s_c2v[adj[d * N_ + v]];
            float tot = lr[k] + mg;
            out[(size_t)BATCH_ * K_ + b * K_ + v] = (tot < 0.0f) ? 1.0f : 0.0f;
        }
    }
}

extern "C" void kernel_launch(void* const* d_in, const int* in_sizes, int n_in,
                              void* d_out, int out_size, void* d_ws, size_t ws_size,
                              hipStream_t stream) {
    const int*   bits    = (const int*)  d_in[0];
    const int*   a_idx   = (const int*)  d_in[1];
    // d_in[2] = edge_cn (implicit: contiguous groups of 6) — unused
    const int*   edge_vn = (const int*)  d_in[3];
    const float* pre     = (const float*)d_in[4];
    const float* pim     = (const float*)d_in[5];
    const float* nre     = (const float*)d_in[6];
    const float* nim     = (const float*)d_in[7];
    const float* ebno    = (const float*)d_in[8];

    char* ws = (char*)d_ws;
    unsigned short* adj = (unsigned short*)ws;                 // DMAX*N u16
    ws += (size_t)DMAX_ * N_ * sizeof(unsigned short);
    unsigned short* vnT = (unsigned short*)ws;                 // ROW*M u16
    ws += (size_t)ROW_ * M_ * sizeof(unsigned short);
    int* deg = (int*)ws;                                       // N i32

    build_adj_kernel<<<N_, 64, 0, stream>>>(edge_vn, adj, vnT, deg);
    link_kernel<<<BATCH_, 256, 0, stream>>>(bits, a_idx, pre, pim, nre, nim,
                                            ebno, adj, vnT, deg, (float*)d_out);
}

// Round 4
// 401.381 us; speedup vs baseline: 3.1827x; 1.1676x over previous
//
#include <hip/hip_runtime.h>

// Problem constants (match reference)
#define K_     1056
#define N_     2112
#define M_     1056   // N - K
#define E_     6336   // M * (DV+1)
#define DV_    5
#define ROW_   6      // DV + 1 edges per check, contiguous
#define NSYM_  528
#define NITER_ 20
#define BATCH_ 1024

// -------------------------------------------------------------------------
// B1: per-VN degree + per-edge rank (ascending-edge order within VN, which
// reproduces np.add.at accumulation order). One 64-lane wave per VN, 4 waves
// per block, edge_vn staged in LDS once per block.
// rankT is indexed by the transposed edge id loc = (e%6)*M + e/6.
// -------------------------------------------------------------------------
__global__ __launch_bounds__(256) void build_rank_kernel(
    const int* __restrict__ edge_vn,
    int* __restrict__ deg,               // [N]
    unsigned short* __restrict__ rankT)  // [ROW][M]
{
    __shared__ int s_evn[E_];
    for (int i = threadIdx.x; i < E_; i += 256) s_evn[i] = edge_vn[i];
    __syncthreads();
    const int wave = threadIdx.x >> 6;
    const int lane = threadIdx.x & 63;
    const int v = blockIdx.x * 4 + wave;
    if (v >= N_) return;
    if (v >= K_) {                        // identity column: degree 1, rank 0
        if (lane == 0) {
            rankT[5 * M_ + (v - K_)] = 0;
            deg[v] = 1;
        }
        return;
    }
    int running = 0;
    for (int w = 0; w < E_ / 64; ++w) {
        int e = w * 64 + lane;
        bool match = (s_evn[e] == v);
        unsigned long long mask = __ballot(match);
        if (match) {
            int rank = running + __popcll(mask & ((1ull << lane) - 1ull));
            int m = e / ROW_, j = e - m * ROW_;
            rankT[j * M_ + m] = (unsigned short)rank;
        }
        running += (int)__popcll(mask);
    }
    if (lane == 0) deg[v] = running;
}

// -------------------------------------------------------------------------
// B2: exclusive prefix sum of deg -> offdeg[v] = off | (deg<<16).
// Single block, Hillis-Steele in LDS (one-off, ~µs).
// -------------------------------------------------------------------------
__global__ __launch_bounds__(1024) void scan_kernel(
    const int* __restrict__ deg,
    unsigned int* __restrict__ offdeg)   // [N]
{
    __shared__ int sa[N_];
    __shared__ int sb[N_];
    int* src = sa;
    int* dst = sb;
    for (int i = threadIdx.x; i < N_; i += 1024) sa[i] = deg[i];
    __syncthreads();
    for (int off = 1; off < N_; off <<= 1) {
        for (int i = threadIdx.x; i < N_; i += 1024)
            dst[i] = src[i] + ((i >= off) ? src[i - off] : 0);
        __syncthreads();
        int* t = src; src = dst; dst = t;
    }
    for (int i = threadIdx.x; i < N_; i += 1024) {
        int excl = (i > 0) ? src[i - 1] : 0;    // src = inclusive scan
        offdeg[i] = (unsigned)excl | ((unsigned)deg[i] << 16);
    }
}

// -------------------------------------------------------------------------
// B3: fuse vn + VN-major position per transposed edge: vp[loc] = vn|(pos<<16)
// -------------------------------------------------------------------------
__global__ __launch_bounds__(256) void build_vp_kernel(
    const int* __restrict__ edge_vn,
    const unsigned int* __restrict__ offdeg,
    const unsigned short* __restrict__ rankT,
    unsigned int* __restrict__ vp)       // [ROW][M]
{
    int e = blockIdx.x * 256 + threadIdx.x;
    if (e >= E_) return;
    int v = edge_vn[e];
    int m = e / ROW_, j = e - m * ROW_;
    int loc = j * M_ + m;
    unsigned pos = (offdeg[v] & 0xFFFFu) + rankT[loc];
    vp[loc] = (unsigned)v | (pos << 16);
}

// -------------------------------------------------------------------------
// One block per codeword. LDS (33.9 KB -> 4 blocks/CU):
//   s_tot[N] : bits -> demapped LLRs -> per-iter VN marginals
//   s_c2v[E] : check->variable messages, VN-MAJOR compact CSR layout
//              (each VN's messages contiguous, ascending edge order)
// All graph indices live in registers across the 20 BP iterations:
//   od[9]     = off|deg<<16 per owned VN      (Phase A: sequential LDS reads)
//   vpr[5][6] = vn|pos<<16  per owned edge    (Phase B: scatter targets)
//   c2vr[5][6]= previous c2v messages         (extrinsic subtract, no LDS read)
// Fast-math identities (HW v_exp/v_log):
//   log(tanh(x/2)) = log((1-e^-x)/(1+e^-x));  2*atanh(y) = log((1+y)/(1-y))
// -------------------------------------------------------------------------
__global__ __launch_bounds__(256, 4) void link_kernel(
    const int*   __restrict__ bits,      // [B,K]
    const int*   __restrict__ a_idx,     // [M,DV]
    const float* __restrict__ points_re, // [16]
    const float* __restrict__ points_im, // [16]
    const float* __restrict__ noise_re,  // [B,NSYM]
    const float* __restrict__ noise_im,  // [B,NSYM]
    const float* __restrict__ ebno_db,   // [1]
    const unsigned int* __restrict__ offdeg, // [N]
    const unsigned int* __restrict__ vp,     // [ROW][M]
    float*       __restrict__ out)       // [2,B,K]
{
#pragma clang fp contract(off)
    const int b   = blockIdx.x;
    const int tid = threadIdx.x;
    const int bs  = blockDim.x;

    __shared__ float s_tot[N_];
    __shared__ float s_c2v[E_];
    __shared__ float s_pre[16];
    __shared__ float s_pim[16];

    if (tid < 16) {
        s_pre[tid] = points_re[tid];
        s_pim[tid] = points_im[tid];
    }

    const float eb    = ebno_db[0];
    const float no    = 1.0f / ((powf(10.0f, eb / 10.0f) * 0.5f) * 4.0f);
    const float sigma = sqrtf(no / 2.0f);

    // ---- stage info bits (0/1 floats); output0 = bits.astype(f32) ----
    for (int i = tid; i < K_; i += bs) {
        int v = bits[b * K_ + i];
        s_tot[i] = (float)v;
        out[b * K_ + i] = (float)v;
    }
    __syncthreads();

    // ---- parity: XOR of DV gathered info bits ----
    for (int m = tid; m < M_; m += bs) {
        float acc = 0.0f;
        #pragma unroll
        for (int d = 0; d < DV_; ++d) acc += s_tot[a_idx[m * DV_ + d]];
        s_tot[K_ + m] = (float)(((int)acc) & 1);
    }
    __syncthreads();

    // ---- iteration-invariant graph indices -> registers ----
    unsigned od[9];
    #pragma unroll
    for (int k = 0; k < 9; ++k) {
        int v = tid + 256 * k;
        od[k] = (v < N_) ? offdeg[v] : 0u;
    }
    unsigned vpr[5][6];
    float    c2vr[5][6];
    #pragma unroll
    for (int kk = 0; kk < 5; ++kk) {
        int m = tid + 256 * kk;
        #pragma unroll
        for (int j = 0; j < ROW_; ++j) {
            vpr[kk][j]  = (m < M_) ? vp[j * M_ + m] : 0u;
            c2vr[kk][j] = 0.0f;
        }
    }

    // ---- QAM map + AWGN + exact APP demap (in-place into s_tot) ----
    for (int s = tid; s < NSYM_; s += bs) {
        int c0 = (int)s_tot[4 * s + 0];
        int c1 = (int)s_tot[4 * s + 1];
        int c2 = (int)s_tot[4 * s + 2];
        int c3 = (int)s_tot[4 * s + 3];
        int sym = c0 * 8 + c1 * 4 + c2 * 2 + c3;
        float yre = s_pre[sym] + sigma * noise_re[b * NSYM_ + s];
        float yim = s_pim[sym] + sigma * noise_im[b * NSYM_ + s];
        float lg[16];
        #pragma unroll
        for (int p = 0; p < 16; ++p) {
            float dre  = yre - s_pre[p];
            float dim_ = yim - s_pim[p];
            float d2   = dre * dre + dim_ * dim_;
            lg[p] = -d2 / no;
        }
        float llr4[4];
        #pragma unroll
        for (int j = 0; j < 4; ++j) {
            float m0 = -1e30f, m1 = -1e30f;
            #pragma unroll
            for (int p = 0; p < 16; ++p) {
                if (((p >> (3 - j)) & 1) == 0) m0 = fmaxf(m0, lg[p]);
                else                           m1 = fmaxf(m1, lg[p]);
            }
            float sum0 = 0.0f, sum1 = 0.0f;
            #pragma unroll
            for (int p = 0; p < 16; ++p) {
                if (((p >> (3 - j)) & 1) == 0) sum0 += __expf(lg[p] - m0);
                else                           sum1 += __expf(lg[p] - m1);
            }
            llr4[j] = (m0 + __logf(sum0)) - (m1 + __logf(sum1));
        }
        s_tot[4 * s + 0] = llr4[0];
        s_tot[4 * s + 1] = llr4[1];
        s_tot[4 * s + 2] = llr4[2];
        s_tot[4 * s + 3] = llr4[3];
    }
    for (int e = tid; e < E_; e += bs) s_c2v[e] = 0.0f;
    __syncthreads();

    // ---- channel LLRs of owned VNs -> registers ----
    float lr[9];
    #pragma unroll
    for (int k = 0; k < 9; ++k) {
        int v = tid + 256 * k;
        lr[k] = (v < N_) ? s_tot[v] : 0.0f;
    }

    // ---- sum-product BP, flooding ----
    for (int it = 0; it < NITER_; ++it) {
        // Phase A: tot[v] = llr[v] + sum of contiguous c2v segment
        // (ascending-edge order == np.add.at order)
        #pragma unroll
        for (int k = 0; k < 9; ++k) {
            int v = tid + 256 * k;
            if (v < N_) {
                int base = (int)(od[k] & 0xFFFFu);
                int dg   = (int)(od[k] >> 16);
                float mg = 0.0f;
                for (int d = 0; d < dg; ++d) mg += s_c2v[base + d];
                s_tot[v] = lr[k] + mg;
            }
        }
        __syncthreads();
        // Phase B: CN update; old c2v from registers, scatter new via pos
        #pragma unroll
        for (int kk = 0; kk < 5; ++kk) {
            int m = tid + 256 * kk;
            if (m < M_) {
                float lt[ROW_];
                float cs = 0.0f;
                int sg = 0;
                #pragma unroll
                for (int j = 0; j < ROW_; ++j) {
                    float v2c = s_tot[vpr[kk][j] & 0xFFFFu] - c2vr[kk][j];
                    float av  = fminf(fmaxf(fabsf(v2c), 1e-6f), 20.0f);
                    float t   = __expf(-av);
                    float l   = __logf(__fdividef(1.0f - t, 1.0f + t));
                    lt[j] = l;
                    sg |= (v2c < 0.0f) ? (1 << j) : 0;
                    cs += l;
                }
                int ns = __popc(sg);
                #pragma unroll
                for (int j = 0; j < ROW_; ++j) {
                    float arg = fminf(cs - lt[j], -1e-7f);
                    float ex  = fminf(__expf(arg), 0.99999994f);   // keep < 1
                    float r   = __logf(__fdividef(1.0f + ex, 1.0f - ex));
                    int sgj = (sg >> j) & 1;
                    if ((ns - sgj) & 1) r = -r;
                    s_c2v[vpr[kk][j] >> 16] = r;
                    c2vr[kk][j] = r;
                }
            }
        }
        __syncthreads();
    }

    // ---- final marginal + hard decision on owned info VNs (coalesced) ----
    #pragma unroll
    for (int k = 0; k < 5; ++k) {
        int v = tid + 256 * k;
        if (v < K_) {
            int base = (int)(od[k] & 0xFFFFu);
            int dg   = (int)(od[k] >> 16);
            float mg = 0.0f;
            for (int d = 0; d < dg; ++d) mg += s_c2v[base + d];
            float tot = lr[k] + mg;
            out[(size_t)BATCH_ * K_ + b * K_ + v] = (tot < 0.0f) ? 1.0f : 0.0f;
        }
    }
}

extern "C" void kernel_launch(void* const* d_in, const int* in_sizes, int n_in,
                              void* d_out, int out_size, void* d_ws, size_t ws_size,
                              hipStream_t stream) {
    const int*   bits    = (const int*)  d_in[0];
    const int*   a_idx   = (const int*)  d_in[1];
    // d_in[2] = edge_cn (implicit: contiguous groups of 6) — unused
    const int*   edge_vn = (const int*)  d_in[3];
    const float* pre     = (const float*)d_in[4];
    const float* pim     = (const float*)d_in[5];
    const float* nre     = (const float*)d_in[6];
    const float* nim     = (const float*)d_in[7];
    const float* ebno    = (const float*)d_in[8];

    char* ws = (char*)d_ws;
    int* deg = (int*)ws;                          ws += (size_t)N_ * sizeof(int);
    unsigned int* offdeg = (unsigned int*)ws;     ws += (size_t)N_ * sizeof(unsigned int);
    unsigned int* vp = (unsigned int*)ws;         ws += (size_t)E_ * sizeof(unsigned int);
    unsigned short* rankT = (unsigned short*)ws;  // E u16

    build_rank_kernel<<<(N_ + 3) / 4, 256, 0, stream>>>(edge_vn, deg, rankT);
    scan_kernel<<<1, 1024, 0, stream>>>(deg, offdeg);
    build_vp_kernel<<<(E_ + 255) / 256, 256, 0, stream>>>(edge_vn, offdeg, rankT, vp);
    link_kernel<<<BATCH_, 256, 0, stream>>>(bits, a_idx, pre, pim, nre, nim,
                                            ebno, offdeg, vp, (float*)d_out);
}